// Round 6
// baseline (119.161 us; speedup 1.0000x reference)
//
#include <hip/hip_runtime.h>

// NonLocalMean: x (4,64,128,128) fp32, K=7 (rad 3), HEADS=4 -> mid=16.
// w_p = exp(2<n_p,c> - ||n_p||^2 - ||c||^2) = exp(-||n_p-c||^2) <= ~1 (the
// softmax max is 0 at the center pixel) -> plain sum, no online rescale.
// out = x + (sum_p w_p n_p)/(sum_p w_p). Zero-padded OOB patches are zero
// vectors contributing exp(-||c||^2) to the denominator.
//
// R6 = R5 + __launch_bounds__(256,4): cap VGPR at 128 -> 4 waves/SIMD
// (16 waves/CU; 21.5KB LDS allows 4 blocks/CU). R5 without the cap likely
// allocated >128 VGPR -> 2 waves/SIMD -> latency-bound at ~26% VALU util
// (R1, the only >60% VALUBusy round, ran 16 waves/CU). R4 showed this cap
// spills ONLY with the full 49-visit unroll; the rolled wy loop here has a
// bounded live set. Everything else unchanged from R5: 1 output/thread,
// bf16 LDS records (8 packed dwords, stride 10 -> b64 bank-pairs (5p+k)%16
// balanced, compile-time offsets), fp32 norms from QUANTIZED values (keeps
// exp<=1 exact), exact-fp32 center from global, stage+norm fused, 1 barrier.

#define TW    16
#define RAD   3
#define HWD   22                 // 16 + 6
#define NPIX  (HWD * HWD)        // 484
#define MID   16
#define PSTRD 10                 // dwords per pixel record (40 B)
#define IMG   128
#define PLANE (IMG * IMG)

__device__ __forceinline__ unsigned bf16rne(float v) {
    unsigned u = __float_as_uint(v);
    u += 0x7fffu + ((u >> 16) & 1u);
    return u >> 16;               // bf16 bits
}

__global__ __launch_bounds__(256, 4)
void nlm_kernel(const float* __restrict__ x, float* __restrict__ out) {
    const int g   = blockIdx.z & 3;
    const int b   = blockIdx.z >> 2;
    const int tx0 = blockIdx.x * TW;
    const int ty0 = blockIdx.y * TW;

    __shared__ __align__(16) unsigned recd[NPIX * PSTRD];  // 19,360 B
    __shared__ float nn[NPIX];                             //  1,936 B

    const int tid = threadIdx.x;
    const int lx  = tid & 15;
    const int ly  = tid >> 4;
    const float* xb = x + (size_t)(b * 64 + g * MID) * PLANE;

    // ---- exact fp32 center (issued early; L2-hot; needed for residual) ----
    const float* cp = xb + (ty0 + ly) * IMG + (tx0 + lx);
    float ctr[MID];
    #pragma unroll
    for (int c = 0; c < MID; ++c) ctr[c] = cp[c * PLANE];
    float ccA = 0.f, ccB = 0.f;
    #pragma unroll
    for (int c = 0; c < MID; c += 2) {
        ccA = fmaf(ctr[c], ctr[c], ccA);
        ccB = fmaf(ctr[c + 1], ctr[c + 1], ccB);
    }
    const float cc = ccA + ccB;

    // ---- stage halo as bf16 + fp32 norms (single pass, one barrier) ----
    #pragma unroll 1
    for (int i = tid; i < NPIX; i += 256) {
        const int yy = i / HWD;
        const int xx = i - yy * HWD;
        const int gy = ty0 + yy - RAD;
        const int gx = tx0 + xx - RAD;
        const bool in = ((unsigned)gy < (unsigned)IMG) & ((unsigned)gx < (unsigned)IMG);
        const float* p = xb + gy * IMG + gx;
        unsigned pk[8];
        float ss = 0.f;
        #pragma unroll
        for (int k = 0; k < 8; ++k) {
            const float v0 = in ? p[(2 * k) * PLANE] : 0.f;
            const float v1 = in ? p[(2 * k + 1) * PLANE] : 0.f;
            const unsigned q0 = bf16rne(v0);
            const unsigned q1 = bf16rne(v1);
            pk[k] = q0 | (q1 << 16);
            const float r0 = __uint_as_float(q0 << 16);
            const float r1 = __uint_as_float(q1 << 16);
            ss = fmaf(r0, r0, ss);
            ss = fmaf(r1, r1, ss);
        }
        unsigned* rp = &recd[i * PSTRD];
        #pragma unroll
        for (int k = 0; k < 4; ++k)
            *reinterpret_cast<uint2*>(rp + 2 * k) = make_uint2(pk[2 * k], pk[2 * k + 1]);
        nn[i] = ss;
    }
    __syncthreads();

    // ---- main: 49 visits, 1 output per thread; wy ROLLED (pressure control) ----
    float acc[MID];
    #pragma unroll
    for (int c = 0; c < MID; ++c) acc[c] = 0.f;
    float s = 0.f;

    #pragma unroll 1
    for (int wy = 0; wy < 7; ++wy) {
        const unsigned* rowp = &recd[((ly + wy) * HWD + lx) * PSTRD];
        const float*    nrow = &nn[(ly + wy) * HWD + lx];
        #pragma unroll
        for (int wx = 0; wx < 7; ++wx) {
            const unsigned* rp = rowp + wx * PSTRD;   // compile-time offset
            const uint2 p0 = *reinterpret_cast<const uint2*>(rp + 0);
            const uint2 p1 = *reinterpret_cast<const uint2*>(rp + 2);
            const uint2 p2 = *reinterpret_cast<const uint2*>(rp + 4);
            const uint2 p3 = *reinterpret_cast<const uint2*>(rp + 6);
            float nb[MID];
            nb[0]  = __uint_as_float(p0.x << 16); nb[1]  = __uint_as_float(p0.x & 0xffff0000u);
            nb[2]  = __uint_as_float(p0.y << 16); nb[3]  = __uint_as_float(p0.y & 0xffff0000u);
            nb[4]  = __uint_as_float(p1.x << 16); nb[5]  = __uint_as_float(p1.x & 0xffff0000u);
            nb[6]  = __uint_as_float(p1.y << 16); nb[7]  = __uint_as_float(p1.y & 0xffff0000u);
            nb[8]  = __uint_as_float(p2.x << 16); nb[9]  = __uint_as_float(p2.x & 0xffff0000u);
            nb[10] = __uint_as_float(p2.y << 16); nb[11] = __uint_as_float(p2.y & 0xffff0000u);
            nb[12] = __uint_as_float(p3.x << 16); nb[13] = __uint_as_float(p3.x & 0xffff0000u);
            nb[14] = __uint_as_float(p3.y << 16); nb[15] = __uint_as_float(p3.y & 0xffff0000u);

            float d0 = 0.f, d1 = 0.f, d2 = 0.f, d3 = 0.f;
            #pragma unroll
            for (int c = 0; c < MID; c += 4) {
                d0 = fmaf(nb[c + 0], ctr[c + 0], d0);
                d1 = fmaf(nb[c + 1], ctr[c + 1], d1);
                d2 = fmaf(nb[c + 2], ctr[c + 2], d2);
                d3 = fmaf(nb[c + 3], ctr[c + 3], d3);
            }
            const float dot = (d0 + d1) + (d2 + d3);
            const float a = fmaf(2.f, dot, -(nrow[wx] + cc));
            const float w = __expf(a);
            s += w;
            #pragma unroll
            for (int c = 0; c < MID; ++c) acc[c] = fmaf(w, nb[c], acc[c]);
        }
    }

    const float inv = 1.f / s;
    float* ob = out + (size_t)(b * 64 + g * MID) * PLANE
                    + (size_t)(ty0 + ly) * IMG + (tx0 + lx);
    #pragma unroll
    for (int c = 0; c < MID; ++c)
        ob[c * PLANE] = fmaf(acc[c], inv, ctr[c]);
}

extern "C" void kernel_launch(void* const* d_in, const int* in_sizes, int n_in,
                              void* d_out, int out_size, void* d_ws, size_t ws_size,
                              hipStream_t stream) {
    const float* x = (const float*)d_in[0];
    float* out = (float*)d_out;
    dim3 grid(IMG / TW, IMG / TW, 16);   // 8 x 8 x (B=4 * HEADS=4) = 1024 blocks
    nlm_kernel<<<grid, 256, 0, stream>>>(x, out);
}

// Round 7
// 34.477 us; speedup vs baseline: 3.4563x; 3.4563x over previous
//
#include <hip/hip_runtime.h>

// NonLocalMean: x (4,64,128,128) fp32, K=7 (rad 3), HEADS=4 -> mid=16.
// w_p = exp(2<n_p,c> - ||n_p||^2 - ||c||^2) = exp(-||n_q - c||^2) <= ~1
// (softmax max is 0 at the center) -> plain sum, no online rescale.
// out = x + (sum_p w_p n_p)/(sum_p w_p); zero-padded OOB patches are zero
// vectors contributing exp(-||c||^2) to the denominator.
//
// R7: register pressure fixed STRUCTURALLY (R4/R6 showed launch_bounds
// caps cause spill disaster; R3/R5 showed uncapped full-unroll >128 VGPR
// -> 2 waves/SIMD -> ~30us latency plateau). The wx loop is rolled with a
// hand-written depth-1 ping-pong: load visit k+1's five ds_read_b64 while
// computing visit k. Only two 5xuint2 load sets can ever be live -> ~100
// VGPR -> 4 waves/SIMD naturally. Norm moved INTO the record (slot 8, read
// as .x of the 5th b64; pair index (5p+4)%16 balanced) -- separate nn array
// and its pointer gone. All loads: one base reg + compile-time imm offsets.

#define TW    16
#define RAD   3
#define HWD   22                 // 16 + 6
#define NPIX  (HWD * HWD)        // 484
#define MID   16
#define PSTRD 10                 // 8 packed-bf16 dwords + norm + pad (40 B)
#define IMG   128
#define PLANE (IMG * IMG)

__device__ __forceinline__ unsigned bf16rne(float v) {
    unsigned u = __float_as_uint(v);
    u += 0x7fffu + ((u >> 16) & 1u);
    return u >> 16;               // bf16 bits
}
__device__ __forceinline__ float bl(unsigned u) { return __uint_as_float(u << 16); }
__device__ __forceinline__ float bh(unsigned u) { return __uint_as_float(u & 0xffff0000u); }

// Load one visit's record: 5 x ds_read_b64, base + imm offsets only.
#define LOADSET(P0, P1, P2, P3, P4, RP, OFF)                                  \
    P0 = *reinterpret_cast<const uint2*>((RP) + (OFF) + 0);                   \
    P1 = *reinterpret_cast<const uint2*>((RP) + (OFF) + 2);                   \
    P2 = *reinterpret_cast<const uint2*>((RP) + (OFF) + 4);                   \
    P3 = *reinterpret_cast<const uint2*>((RP) + (OFF) + 6);                   \
    P4 = *reinterpret_cast<const uint2*>((RP) + (OFF) + 8);

#define VISITSET(P0, P1, P2, P3, P4)                                          \
    {                                                                         \
        float nb[MID];                                                        \
        nb[0]  = bl(P0.x); nb[1]  = bh(P0.x);                                 \
        nb[2]  = bl(P0.y); nb[3]  = bh(P0.y);                                 \
        nb[4]  = bl(P1.x); nb[5]  = bh(P1.x);                                 \
        nb[6]  = bl(P1.y); nb[7]  = bh(P1.y);                                 \
        nb[8]  = bl(P2.x); nb[9]  = bh(P2.x);                                 \
        nb[10] = bl(P2.y); nb[11] = bh(P2.y);                                 \
        nb[12] = bl(P3.x); nb[13] = bh(P3.x);                                 \
        nb[14] = bl(P3.y); nb[15] = bh(P3.y);                                 \
        float d0 = 0.f, d1 = 0.f, d2 = 0.f, d3 = 0.f;                         \
        _Pragma("unroll")                                                     \
        for (int c = 0; c < MID; c += 4) {                                    \
            d0 = fmaf(nb[c + 0], ctr[c + 0], d0);                             \
            d1 = fmaf(nb[c + 1], ctr[c + 1], d1);                             \
            d2 = fmaf(nb[c + 2], ctr[c + 2], d2);                             \
            d3 = fmaf(nb[c + 3], ctr[c + 3], d3);                             \
        }                                                                     \
        const float dot = (d0 + d1) + (d2 + d3);                              \
        const float nv  = __uint_as_float(P4.x);                              \
        const float w   = __expf(fmaf(2.f, dot, -(nv + cc)));                 \
        s += w;                                                               \
        _Pragma("unroll")                                                     \
        for (int c = 0; c < MID; ++c) acc[c] = fmaf(w, nb[c], acc[c]);        \
    }

__global__ __launch_bounds__(256)
void nlm_kernel(const float* __restrict__ x, float* __restrict__ out) {
    const int g   = blockIdx.z & 3;
    const int b   = blockIdx.z >> 2;
    const int tx0 = blockIdx.x * TW;
    const int ty0 = blockIdx.y * TW;

    __shared__ __align__(16) unsigned recd[NPIX * PSTRD];  // 19,360 B

    const int tid = threadIdx.x;
    const int lx  = tid & 15;
    const int ly  = tid >> 4;
    const float* xb = x + (size_t)(b * 64 + g * MID) * PLANE;

    // ---- exact fp32 center (residual + dot accuracy) ----
    const float* cp = xb + (ty0 + ly) * IMG + (tx0 + lx);
    float ctr[MID];
    #pragma unroll
    for (int c = 0; c < MID; ++c) ctr[c] = cp[c * PLANE];
    float ccA = 0.f, ccB = 0.f;
    #pragma unroll
    for (int c = 0; c < MID; c += 2) {
        ccA = fmaf(ctr[c], ctr[c], ccA);
        ccB = fmaf(ctr[c + 1], ctr[c + 1], ccB);
    }
    const float cc = ccA + ccB;

    // ---- stage halo: bf16-packed channels + fp32 norm in slot 8 ----
    #pragma unroll 1
    for (int i = tid; i < NPIX; i += 256) {
        const int yy = i / HWD;
        const int xx = i - yy * HWD;
        const int gy = ty0 + yy - RAD;
        const int gx = tx0 + xx - RAD;
        const bool in = ((unsigned)gy < (unsigned)IMG) & ((unsigned)gx < (unsigned)IMG);
        const float* p = xb + gy * IMG + gx;
        unsigned pk[8];
        float ss = 0.f;
        #pragma unroll
        for (int k = 0; k < 8; ++k) {
            const float v0 = in ? p[(2 * k) * PLANE] : 0.f;
            const float v1 = in ? p[(2 * k + 1) * PLANE] : 0.f;
            const unsigned q0 = bf16rne(v0);
            const unsigned q1 = bf16rne(v1);
            pk[k] = q0 | (q1 << 16);
            const float r0 = bl(q0 << 16 >> 16 << 16);  // quantized value
            const float r1 = __uint_as_float(q1 << 16);
            const float r0f = __uint_as_float(q0 << 16);
            ss = fmaf(r0f, r0f, ss);
            ss = fmaf(r1, r1, ss);
            (void)r0;
        }
        unsigned* rp = &recd[i * PSTRD];
        #pragma unroll
        for (int k = 0; k < 4; ++k)
            *reinterpret_cast<uint2*>(rp + 2 * k) = make_uint2(pk[2 * k], pk[2 * k + 1]);
        *reinterpret_cast<uint2*>(rp + 8) = make_uint2(__float_as_uint(ss), 0u);
    }
    __syncthreads();

    // ---- main: 49 visits, depth-1 ping-pong over rolled wx ----
    float acc[MID];
    #pragma unroll
    for (int c = 0; c < MID; ++c) acc[c] = 0.f;
    float s = 0.f;

    #pragma unroll 1
    for (int wy = 0; wy < 7; ++wy) {
        const unsigned* rp = &recd[((ly + wy) * HWD + lx) * PSTRD];
        uint2 a0, a1, a2, a3, a4, b0, b1, b2, b3, b4;
        LOADSET(a0, a1, a2, a3, a4, rp, 0)
        #pragma unroll 1
        for (int wx = 0; wx < 6; wx += 2) {
            LOADSET(b0, b1, b2, b3, b4, rp, PSTRD)       // visit wx+1
            VISITSET(a0, a1, a2, a3, a4)                 // visit wx
            LOADSET(a0, a1, a2, a3, a4, rp, 2 * PSTRD)   // visit wx+2 (<=6)
            VISITSET(b0, b1, b2, b3, b4)                 // visit wx+1
            rp += 2 * PSTRD;
        }
        VISITSET(a0, a1, a2, a3, a4)                     // visit wx = 6
    }

    const float inv = 1.f / s;
    float* ob = out + (size_t)(b * 64 + g * MID) * PLANE
                    + (size_t)(ty0 + ly) * IMG + (tx0 + lx);
    #pragma unroll
    for (int c = 0; c < MID; ++c)
        ob[c * PLANE] = fmaf(acc[c], inv, ctr[c]);
}

extern "C" void kernel_launch(void* const* d_in, const int* in_sizes, int n_in,
                              void* d_out, int out_size, void* d_ws, size_t ws_size,
                              hipStream_t stream) {
    const float* x = (const float*)d_in[0];
    float* out = (float*)d_out;
    dim3 grid(IMG / TW, IMG / TW, 16);   // 8 x 8 x (B=4 * HEADS=4) = 1024 blocks
    nlm_kernel<<<grid, 256, 0, stream>>>(x, out);
}